// Round 4
// baseline (117.846 us; speedup 1.0000x reference)
//
#include <hip/hip_runtime.h>
#include <hip/hip_bf16.h>

#define ALPHA 100.0f

// Per-triangle precomputed invariants: 6 x float4 = 96 B
//  q0: v0.xyz, dt  (dt = area-OK ? max(area2,1e-12) : -1  -> folds flag into u+v test)
//  q1: e0.xyz, dot00
//  q2: e1.xyz, dot11
//  q3: nn.xyz (n * rsqrt(max(area2,1e-12))),  dot01
//  q4: inv00, inv11, c12(=dot00-dot01), invab
//  q5: abab(=dot00-2dot01+dot11), 0, 0, 0

__global__ __launch_bounds__(256) void rast_pre(const float* __restrict__ tv,
                                                float4* __restrict__ pre) {
    int i = blockIdx.x * 256 + threadIdx.x;   // 0..4095 triangles (4 batches x 1024)
    if (i >= 4096) return;
    const float* t = tv + (size_t)i * 9;
    float v0x = t[0], v0y = t[1], v0z = t[2];
    float v1x = t[3], v1y = t[4], v1z = t[5];
    float v2x = t[6], v2y = t[7], v2z = t[8];

    float e0x = v1x - v0x, e0y = v1y - v0y, e0z = v1z - v0z;
    float e1x = v2x - v0x, e1y = v2y - v0y, e1z = v2z - v0z;

    float nx = e0y * e1z - e0z * e1y;
    float ny = e0z * e1x - e0x * e1z;
    float nz = e0x * e1y - e0y * e1x;
    float area2 = nx * nx + ny * ny + nz * nz;

    float dot00 = e0x * e0x + e0y * e0y + e0z * e0z;
    float dot01 = e0x * e1x + e0y * e1y + e0z * e1z;
    float dot11 = e1x * e1x + e1y * e1y + e1z * e1z;

    float denom = fmaxf(area2, 1e-12f);
    double rs   = 1.0 / sqrt((double)denom);
    float nnx = (float)(nx * rs), nny = (float)(ny * rs), nnz = (float)(nz * rs);

    float inv00 = 1.0f / fmaxf(dot00, 1e-12f);
    float inv11 = 1.0f / fmaxf(dot11, 1e-12f);
    float abab  = dot00 - 2.0f * dot01 + dot11;
    float invab = 1.0f / fmaxf(abab, 1e-12f);
    float dt    = (area2 >= 4e-10f) ? denom : -1.0f;   // 4 * (1e-5)^2
    float c12   = dot00 - dot01;

    float4* q = pre + (size_t)i * 6;
    q[0] = make_float4(v0x, v0y, v0z, dt);
    q[1] = make_float4(e0x, e0y, e0z, dot00);
    q[2] = make_float4(e1x, e1y, e1z, dot11);
    q[3] = make_float4(nnx, nny, nnz, dot01);
    q[4] = make_float4(inv00, inv11, c12, invab);
    q[5] = make_float4(abab, 0.0f, 0.0f, 0.0f);
}

__device__ __forceinline__ void tri_body(float px, float py, float pz,
                                         float4 q0, float4 q1, float4 q2,
                                         float4 q3, float4 q4, float4 q5,
                                         float& dmin) {
    float dx = px - q0.x, dy = py - q0.y, dz = pz - q0.z;
    float dd = dx * dx + dy * dy + dz * dz;
    float a0 = q1.x * dx + q1.y * dy + q1.z * dz;   // dot(e0, d)
    float a1 = q2.x * dx + q2.y * dy + q2.z * dz;   // dot(e1, d)
    float dn = q3.x * dx + q3.y * dy + q3.z * dz;   // dot(n_scaled, d)

    float dot00 = q1.w, dot11 = q2.w, dot01 = q3.w, dt = q0.w;
    float inv00 = q4.x, inv11 = q4.y, c12 = q4.z, invab = q4.w;
    float abab = q5.x;

    // inside test, unnormalized: U>=0 && V>=0 && U+V<=dt  (dt=-1 kills degenerate)
    float U = dot11 * a0 - dot01 * a1;
    float V = dot00 * a1 - dot01 * a0;
    float m3 = fminf(fminf(U, V), dt - (U + V));    // v_min3
    float plane = dn * dn;

    float a02 = a0 + a0;
    float t1 = fminf(fmaxf(a0 * inv00, 0.0f), 1.0f);   // v_med3
    float s1 = dd + t1 * (t1 * dot00 - a02);
    float a12 = a1 + a1;
    float t2 = fminf(fmaxf(a1 * inv11, 0.0f), 1.0f);
    float s2 = dd + t2 * (t2 * dot11 - a12);
    float pab  = c12 + a1 - a0;            // dot(p-v1, v2-v1)
    float papa = (dd - a02) + dot00;       // |p-v1|^2
    float t3 = fminf(fmaxf(pab * invab, 0.0f), 1.0f);
    float s3 = papa + t3 * (t3 * abab - (pab + pab));

    float edge = fminf(fminf(s1, s2), s3);  // v_min3
    float r = (m3 >= 0.0f) ? plane : edge;
    dmin = fminf(dmin, r);
}

// Grid: 512 blocks x 1024 threads (16 waves).
// block -> (batch = blockIdx>>7, point-block = blockIdx&127 -> 64 points)
// lane (0..63) = point; wave (0..15) = 64-triangle chunk. 2 blocks/CU -> 32 waves/CU.
// Inner loop software-pipelined 1 deep: iteration k computes while k+1's 96 B
// of invariants are in flight on the scalar-load pipe.
__global__ __launch_bounds__(1024) void rast_main(const float* __restrict__ pts,
                                                  const float4* __restrict__ pre,
                                                  float* __restrict__ out) {
    int b    = blockIdx.x >> 7;
    int pblk = blockIdx.x & 127;
    int lane = threadIdx.x & 63;
    int wave = __builtin_amdgcn_readfirstlane((int)(threadIdx.x >> 6));  // 0..15

    int point = pblk * 64 + lane;
    const float* pp = pts + ((size_t)b * 8192 + point) * 3;
    float px = pp[0], py = pp[1], pz = pp[2];

    const float4* tp = pre + ((size_t)b * 1024 + (size_t)wave * 64) * 6;

    float dmin = 3.4e38f;

    float4 c0 = tp[0], c1 = tp[1], c2 = tp[2], c3 = tp[3], c4 = tp[4], c5 = tp[5];
#pragma unroll 3
    for (int k = 0; k < 63; ++k) {
        tp += 6;
        // prefetch k+1 (issues s_loads before the body's VALU work)
        float4 n0 = tp[0], n1 = tp[1], n2 = tp[2], n3 = tp[3], n4 = tp[4], n5 = tp[5];
        tri_body(px, py, pz, c0, c1, c2, c3, c4, c5, dmin);
        c0 = n0; c1 = n1; c2 = n2; c3 = n3; c4 = n4; c5 = n5;
    }
    tri_body(px, py, pz, c0, c1, c2, c3, c4, c5, dmin);

    __shared__ float red[1024];
    red[threadIdx.x] = dmin;
    __syncthreads();
    if (threadIdx.x < 64) {
        float m = red[threadIdx.x];
#pragma unroll
        for (int w = 1; w < 16; ++w) m = fminf(m, red[w * 64 + threadIdx.x]);
        out[(size_t)b * 8192 + pblk * 64 + threadIdx.x] = __expf(-ALPHA * m);
    }
}

extern "C" void kernel_launch(void* const* d_in, const int* in_sizes, int n_in,
                              void* d_out, int out_size, void* d_ws, size_t ws_size,
                              hipStream_t stream) {
    const float* pts = (const float*)d_in[0];   // (4, 8192, 3)
    const float* tv  = (const float*)d_in[1];   // (4, 1024, 3, 3)
    float* out = (float*)d_out;                 // (4, 8192)
    float4* pre = (float4*)d_ws;                // 4096 * 6 float4 = 384 KB

    rast_pre<<<16, 256, 0, stream>>>(tv, pre);
    rast_main<<<512, 1024, 0, stream>>>(pts, pre, out);
}

// Round 5
// 112.712 us; speedup vs baseline: 1.0456x; 1.0456x over previous
//
#include <hip/hip_runtime.h>
#include <hip/hip_bf16.h>

#define ALPHA 100.0f

// Per-triangle precomputed invariants: 6 x float4 = 96 B
//  q0: v0.xyz, dt  (dt = area-OK ? max(area2,1e-12) : -1  -> folds flag into u+v test)
//  q1: e0.xyz, dot00
//  q2: e1.xyz, dot11
//  q3: nn.xyz (n * rsqrt(max(area2,1e-12))),  dot01
//  q4: inv00, inv11, c12(=dot00-dot01), invab
//  q5: abab(=dot00-2dot01+dot11), 0, 0, 0

__global__ __launch_bounds__(256) void rast_pre(const float* __restrict__ tv,
                                                float4* __restrict__ pre) {
    int i = blockIdx.x * 256 + threadIdx.x;   // 0..4095 triangles (4 batches x 1024)
    if (i >= 4096) return;
    const float* t = tv + (size_t)i * 9;
    float v0x = t[0], v0y = t[1], v0z = t[2];
    float v1x = t[3], v1y = t[4], v1z = t[5];
    float v2x = t[6], v2y = t[7], v2z = t[8];

    float e0x = v1x - v0x, e0y = v1y - v0y, e0z = v1z - v0z;
    float e1x = v2x - v0x, e1y = v2y - v0y, e1z = v2z - v0z;

    float nx = e0y * e1z - e0z * e1y;
    float ny = e0z * e1x - e0x * e1z;
    float nz = e0x * e1y - e0y * e1x;
    float area2 = nx * nx + ny * ny + nz * nz;

    float dot00 = e0x * e0x + e0y * e0y + e0z * e0z;
    float dot01 = e0x * e1x + e0y * e1y + e0z * e1z;
    float dot11 = e1x * e1x + e1y * e1y + e1z * e1z;

    float denom = fmaxf(area2, 1e-12f);
    double rs   = 1.0 / sqrt((double)denom);
    float nnx = (float)(nx * rs), nny = (float)(ny * rs), nnz = (float)(nz * rs);

    float inv00 = 1.0f / fmaxf(dot00, 1e-12f);
    float inv11 = 1.0f / fmaxf(dot11, 1e-12f);
    float abab  = dot00 - 2.0f * dot01 + dot11;
    float invab = 1.0f / fmaxf(abab, 1e-12f);
    float dt    = (area2 >= 4e-10f) ? denom : -1.0f;   // 4 * (1e-5)^2
    float c12   = dot00 - dot01;

    float4* q = pre + (size_t)i * 6;
    q[0] = make_float4(v0x, v0y, v0z, dt);
    q[1] = make_float4(e0x, e0y, e0z, dot00);
    q[2] = make_float4(e1x, e1y, e1z, dot11);
    q[3] = make_float4(nnx, nny, nnz, dot01);
    q[4] = make_float4(inv00, inv11, c12, invab);
    q[5] = make_float4(abab, 0.0f, 0.0f, 0.0f);
}

__device__ __forceinline__ void tri_body(float px, float py, float pz,
                                         const float4& q0, const float4& q1,
                                         const float4& q2, const float4& q3,
                                         const float4& q4, const float4& q5,
                                         float& dmin) {
    float dx = px - q0.x, dy = py - q0.y, dz = pz - q0.z;
    float dd = dx * dx + dy * dy + dz * dz;
    float a0 = q1.x * dx + q1.y * dy + q1.z * dz;   // dot(e0, d)
    float a1 = q2.x * dx + q2.y * dy + q2.z * dz;   // dot(e1, d)
    float dn = q3.x * dx + q3.y * dy + q3.z * dz;   // dot(n_scaled, d)

    float dot00 = q1.w, dot11 = q2.w, dot01 = q3.w, dt = q0.w;
    float inv00 = q4.x, inv11 = q4.y, c12 = q4.z, invab = q4.w;
    float abab = q5.x;

    // inside test, unnormalized: U>=0 && V>=0 && U+V<=dt  (dt=-1 kills degenerate)
    float U = dot11 * a0 - dot01 * a1;
    float V = dot00 * a1 - dot01 * a0;
    float m3 = fminf(fminf(U, V), dt - (U + V));    // v_min3
    float plane = dn * dn;

    float a02 = a0 + a0;
    float t1 = fminf(fmaxf(a0 * inv00, 0.0f), 1.0f);   // v_med3
    float s1 = dd + t1 * (t1 * dot00 - a02);
    float a12 = a1 + a1;
    float t2 = fminf(fmaxf(a1 * inv11, 0.0f), 1.0f);
    float s2 = dd + t2 * (t2 * dot11 - a12);
    float pab  = c12 + a1 - a0;            // dot(p-v1, v2-v1)
    float papa = (dd - a02) + dot00;       // |p-v1|^2
    float t3 = fminf(fmaxf(pab * invab, 0.0f), 1.0f);
    float s3 = papa + t3 * (t3 * abab - (pab + pab));

    float edge = fminf(fminf(s1, s2), s3);  // v_min3
    float r = (m3 >= 0.0f) ? plane : edge;
    dmin = fminf(dmin, r);
}

// Grid: 256 blocks x 1024 threads (16 waves). 1 block/CU.
// block -> (batch = blockIdx>>6, point-group = blockIdx&63 -> 128 points)
// lane (0..63) owns points {lane, lane+64} of the group (2 per lane).
// wave (0..15) owns a 64-triangle chunk; triangle invariants are wave-uniform
// scalar loads amortized over 2x48 VALU ops -> ~89% useful issue slots.
__global__ __launch_bounds__(1024) void rast_main(const float* __restrict__ pts,
                                                  const float4* __restrict__ pre,
                                                  float* __restrict__ out) {
    int b    = blockIdx.x >> 6;
    int pg   = blockIdx.x & 63;
    int lane = threadIdx.x & 63;
    int wave = __builtin_amdgcn_readfirstlane((int)(threadIdx.x >> 6));  // 0..15

    int base = (b << 13) + (pg << 7);           // b*8192 + pg*128
    const float* pp0 = pts + (size_t)(base + lane) * 3;
    const float* pp1 = pts + (size_t)(base + 64 + lane) * 3;
    float px0 = pp0[0], py0 = pp0[1], pz0 = pp0[2];
    float px1 = pp1[0], py1 = pp1[1], pz1 = pp1[2];

    const float4* tp = pre + ((size_t)b * 1024 + (size_t)wave * 64) * 6;

    float d0 = 3.4e38f, d1 = 3.4e38f;
#pragma unroll 2
    for (int k = 0; k < 64; ++k) {
        float4 q0 = tp[0];
        float4 q1 = tp[1];
        float4 q2 = tp[2];
        float4 q3 = tp[3];
        float4 q4 = tp[4];
        float4 q5 = tp[5];
        tp += 6;
        tri_body(px0, py0, pz0, q0, q1, q2, q3, q4, q5, d0);
        tri_body(px1, py1, pz1, q0, q1, q2, q3, q4, q5, d1);
    }

    // red[wave][point_local]: consecutive lanes -> consecutive words, no conflicts
    __shared__ float red[16 * 128];
    red[wave * 128 + lane]      = d0;
    red[wave * 128 + lane + 64] = d1;
    __syncthreads();
    if (threadIdx.x < 128) {
        float m = red[threadIdx.x];
#pragma unroll
        for (int w = 1; w < 16; ++w) m = fminf(m, red[w * 128 + threadIdx.x]);
        out[base + threadIdx.x] = __expf(-ALPHA * m);
    }
}

extern "C" void kernel_launch(void* const* d_in, const int* in_sizes, int n_in,
                              void* d_out, int out_size, void* d_ws, size_t ws_size,
                              hipStream_t stream) {
    const float* pts = (const float*)d_in[0];   // (4, 8192, 3)
    const float* tv  = (const float*)d_in[1];   // (4, 1024, 3, 3)
    float* out = (float*)d_out;                 // (4, 8192)
    float4* pre = (float4*)d_ws;                // 4096 * 6 float4 = 384 KB

    rast_pre<<<16, 256, 0, stream>>>(tv, pre);
    rast_main<<<256, 1024, 0, stream>>>(pts, pre, out);
}

// Round 7
// 90.115 us; speedup vs baseline: 1.3077x; 1.2508x over previous
//
#include <hip/hip_runtime.h>
#include <hip/hip_bf16.h>

#define ALPHA 100.0f

typedef float v2f __attribute__((ext_vector_type(2)));

// Per-triangle precomputed invariants: 6 x float4 = 96 B  (same layout as before)
//  q0: v0.xyz, dt   q1: e0.xyz, dot00   q2: e1.xyz, dot11
//  q3: nn.xyz, dot01 (nn = n * rsqrt(denom))
//  q4: inv00, inv11, c12, invab   q5: abab, -, -, -
__global__ __launch_bounds__(256) void rast_pre(const float* __restrict__ tv,
                                                float4* __restrict__ pre) {
    int i = blockIdx.x * 256 + threadIdx.x;   // 0..4095
    if (i >= 4096) return;
    const float* t = tv + (size_t)i * 9;
    float v0x = t[0], v0y = t[1], v0z = t[2];
    float v1x = t[3], v1y = t[4], v1z = t[5];
    float v2x = t[6], v2y = t[7], v2z = t[8];

    float e0x = v1x - v0x, e0y = v1y - v0y, e0z = v1z - v0z;
    float e1x = v2x - v0x, e1y = v2y - v0y, e1z = v2z - v0z;

    float nx = e0y * e1z - e0z * e1y;
    float ny = e0z * e1x - e0x * e1z;
    float nz = e0x * e1y - e0y * e1x;
    float area2 = nx * nx + ny * ny + nz * nz;

    float dot00 = e0x * e0x + e0y * e0y + e0z * e0z;
    float dot01 = e0x * e1x + e0y * e1y + e0z * e1z;
    float dot11 = e1x * e1x + e1y * e1y + e1z * e1z;

    float denom = fmaxf(area2, 1e-12f);
    double rs   = 1.0 / sqrt((double)denom);
    float nnx = (float)(nx * rs), nny = (float)(ny * rs), nnz = (float)(nz * rs);

    float inv00 = 1.0f / fmaxf(dot00, 1e-12f);
    float inv11 = 1.0f / fmaxf(dot11, 1e-12f);
    float abab  = dot00 - 2.0f * dot01 + dot11;
    float invab = 1.0f / fmaxf(abab, 1e-12f);
    float dt    = (area2 >= 4e-10f) ? denom : -1.0f;
    float c12   = dot00 - dot01;

    float4* q = pre + (size_t)i * 6;
    q[0] = make_float4(v0x, v0y, v0z, dt);
    q[1] = make_float4(e0x, e0y, e0z, dot00);
    q[2] = make_float4(e1x, e1y, e1z, dot11);
    q[3] = make_float4(nnx, nny, nnz, dot01);
    q[4] = make_float4(inv00, inv11, c12, invab);
    q[5] = make_float4(abab, 0.0f, 0.0f, 0.0f);
}

// Two triangles packed as float2 halves -> v_pk_*_f32 processes both.
struct TP {
    v2f v0x, v0y, v0z, dt;
    v2f e0x, e0y, e0z, d00;
    v2f e1x, e1y, e1z, d11;
    v2f nnx, nny, nnz, d01;
    v2f i00, i11, c12, iab;
    v2f ab;
};

__device__ __forceinline__ void load_pair(const float4* __restrict__ p6,
                                          int ta, int tb, TP& t) {
    const float4* qa = p6 + (size_t)ta * 6;
    const float4* qb = p6 + (size_t)tb * 6;
    float4 a0 = qa[0], a1 = qa[1], a2 = qa[2], a3 = qa[3], a4 = qa[4], a5 = qa[5];
    float4 b0 = qb[0], b1 = qb[1], b2 = qb[2], b3 = qb[3], b4 = qb[4], b5 = qb[5];
    t.v0x = (v2f){a0.x, b0.x}; t.v0y = (v2f){a0.y, b0.y}; t.v0z = (v2f){a0.z, b0.z}; t.dt  = (v2f){a0.w, b0.w};
    t.e0x = (v2f){a1.x, b1.x}; t.e0y = (v2f){a1.y, b1.y}; t.e0z = (v2f){a1.z, b1.z}; t.d00 = (v2f){a1.w, b1.w};
    t.e1x = (v2f){a2.x, b2.x}; t.e1y = (v2f){a2.y, b2.y}; t.e1z = (v2f){a2.z, b2.z}; t.d11 = (v2f){a2.w, b2.w};
    t.nnx = (v2f){a3.x, b3.x}; t.nny = (v2f){a3.y, b3.y}; t.nnz = (v2f){a3.z, b3.z}; t.d01 = (v2f){a3.w, b3.w};
    t.i00 = (v2f){a4.x, b4.x}; t.i11 = (v2f){a4.y, b4.y}; t.c12 = (v2f){a4.z, b4.z}; t.iab = (v2f){a4.w, b4.w};
    t.ab  = (v2f){a5.x, b5.x};
}

__device__ __forceinline__ float readlane_f(float v, int l) {
    return __uint_as_float(__builtin_amdgcn_readlane(__float_as_uint(v), l));
}

// point (wave-uniform scalars) vs 2 packed triangles; accumulates into dmin halves
__device__ __forceinline__ void pair_body(float px, float py, float pz,
                                          const TP& g, v2f& dmin) {
    v2f dx = px - g.v0x, dy = py - g.v0y, dz = pz - g.v0z;
    v2f dd = dx * dx + dy * dy + dz * dz;
    v2f a0 = g.e0x * dx + g.e0y * dy + g.e0z * dz;
    v2f a1 = g.e1x * dx + g.e1y * dy + g.e1z * dz;
    v2f dn = g.nnx * dx + g.nny * dy + g.nnz * dz;

    v2f U = g.d11 * a0 - g.d01 * a1;
    v2f V = g.d00 * a1 - g.d01 * a0;
    v2f W = g.dt - (U + V);
    v2f plane = dn * dn;

    v2f a02 = a0 + a0;
    v2f m1 = a0 * g.i00;
    v2f t1; t1.x = fminf(fmaxf(m1.x, 0.f), 1.f); t1.y = fminf(fmaxf(m1.y, 0.f), 1.f);
    v2f s1 = dd + t1 * (t1 * g.d00 - a02);
    v2f a12 = a1 + a1;
    v2f m2 = a1 * g.i11;
    v2f t2; t2.x = fminf(fmaxf(m2.x, 0.f), 1.f); t2.y = fminf(fmaxf(m2.y, 0.f), 1.f);
    v2f s2 = dd + t2 * (t2 * g.d11 - a12);
    v2f pab  = (g.c12 + a1) - a0;
    v2f papa = (dd - a02) + g.d00;
    v2f m3 = pab * g.iab;
    v2f t3; t3.x = fminf(fmaxf(m3.x, 0.f), 1.f); t3.y = fminf(fmaxf(m3.y, 0.f), 1.f);
    v2f s3 = papa + t3 * (t3 * g.ab - (pab + pab));

    float ex = fminf(fminf(s1.x, s2.x), s3.x);           // v_min3
    float ey = fminf(fminf(s1.y, s2.y), s3.y);
    float ix = fminf(fminf(U.x, V.x), W.x);              // v_min3
    float iy = fminf(fminf(U.y, V.y), W.y);
    float rx = (ix >= 0.f) ? plane.x : ex;
    float ry = (iy >= 0.f) ? plane.y : ey;
    dmin.x = fminf(dmin.x, rx);
    dmin.y = fminf(dmin.y, ry);
}

// Grid: 1024 blocks x 256 threads (4 waves). 4 blocks/CU.
// block -> (batch = blockIdx>>8, point-group = blockIdx&255 -> 32 points).
// lane = triangle slot: wave w holds tris w*256 + {lane, lane+64, lane+128, lane+192}
// in REGISTERS (two packed TP pairs). Inner loop over 32 points has ZERO memory ops:
// point broadcast via v_readlane, min-reduce via shfl_xor within 32-lane halves.
__global__ __launch_bounds__(256) void rast_main(const float* __restrict__ pts,
                                                 const float4* __restrict__ pre,
                                                 float* __restrict__ out) {
    int b    = blockIdx.x >> 8;
    int pg   = blockIdx.x & 255;
    int base = (b << 13) + (pg << 5);            // b*8192 + pg*32
    int lane = threadIdx.x & 63;
    int wave = __builtin_amdgcn_readfirstlane((int)(threadIdx.x >> 6));  // 0..3

    const float4* p6 = pre + (size_t)b * 1024 * 6;
    int t0 = wave * 256 + lane;

    TP g0, g1;
    load_pair(p6, t0,        t0 + 64,  g0);
    load_pair(p6, t0 + 128,  t0 + 192, g1);

    // 32 points of this group live in lanes 0..31 (duplicated in 32..63)
    int pl = lane & 31;
    const float* pp = pts + (size_t)(base + pl) * 3;
    float pxv = pp[0], pyv = pp[1], pzv = pp[2];

    __shared__ float red[8][32];

    for (int j = 0; j < 32; j += 2) {
        float pxA = readlane_f(pxv, j),     pyA = readlane_f(pyv, j),     pzA = readlane_f(pzv, j);
        float pxB = readlane_f(pxv, j + 1), pyB = readlane_f(pyv, j + 1), pzB = readlane_f(pzv, j + 1);

        v2f dA = (v2f){3.4e38f, 3.4e38f};
        v2f dB = (v2f){3.4e38f, 3.4e38f};
        pair_body(pxA, pyA, pzA, g0, dA);
        pair_body(pxA, pyA, pzA, g1, dA);
        pair_body(pxB, pyB, pzB, g0, dB);
        pair_body(pxB, pyB, pzB, g1, dB);

        float a = fminf(dA.x, dA.y);
        float c = fminf(dB.x, dB.y);
#pragma unroll
        for (int m = 16; m >= 1; m >>= 1) {
            a = fminf(a, __shfl_xor(a, m, 64));
            c = fminf(c, __shfl_xor(c, m, 64));
        }
        if ((lane & 31) == 0) {            // lane 0: min of lanes 0..31; lane 32: 32..63
            int h = lane >> 5;
            red[2 * wave + h][j]     = a;
            red[2 * wave + h][j + 1] = c;
        }
    }
    __syncthreads();
    if (threadIdx.x < 32) {
        float m = red[0][threadIdx.x];
#pragma unroll
        for (int k = 1; k < 8; ++k) m = fminf(m, red[k][threadIdx.x]);
        out[base + threadIdx.x] = __expf(-ALPHA * m);
    }
}

extern "C" void kernel_launch(void* const* d_in, const int* in_sizes, int n_in,
                              void* d_out, int out_size, void* d_ws, size_t ws_size,
                              hipStream_t stream) {
    const float* pts = (const float*)d_in[0];   // (4, 8192, 3)
    const float* tv  = (const float*)d_in[1];   // (4, 1024, 3, 3)
    float* out = (float*)d_out;                 // (4, 8192)
    float4* pre = (float4*)d_ws;                // 4096 * 6 float4 = 384 KB

    rast_pre<<<16, 256, 0, stream>>>(tv, pre);
    rast_main<<<1024, 256, 0, stream>>>(pts, pre, out);
}

// Round 8
// 87.369 us; speedup vs baseline: 1.3488x; 1.0314x over previous
//
#include <hip/hip_runtime.h>
#include <hip/hip_bf16.h>

#define ALPHA 100.0f

typedef float v2f __attribute__((ext_vector_type(2)));

// Per-triangle precomputed invariants: 6 x float4 = 96 B
//  q0: v0.xyz, dt   q1: e0.xyz, dot00   q2: e1.xyz, dot11
//  q3: nn.xyz, dot01 (nn = n * rsqrt(denom))
//  q4: inv00, inv11, c12, invab   q5: abab, -, -, -
__global__ __launch_bounds__(256) void rast_pre(const float* __restrict__ tv,
                                                float4* __restrict__ pre) {
    int i = blockIdx.x * 256 + threadIdx.x;   // 0..4095
    if (i >= 4096) return;
    const float* t = tv + (size_t)i * 9;
    float v0x = t[0], v0y = t[1], v0z = t[2];
    float v1x = t[3], v1y = t[4], v1z = t[5];
    float v2x = t[6], v2y = t[7], v2z = t[8];

    float e0x = v1x - v0x, e0y = v1y - v0y, e0z = v1z - v0z;
    float e1x = v2x - v0x, e1y = v2y - v0y, e1z = v2z - v0z;

    float nx = e0y * e1z - e0z * e1y;
    float ny = e0z * e1x - e0x * e1z;
    float nz = e0x * e1y - e0y * e1x;
    float area2 = nx * nx + ny * ny + nz * nz;

    float dot00 = e0x * e0x + e0y * e0y + e0z * e0z;
    float dot01 = e0x * e1x + e0y * e1y + e0z * e1z;
    float dot11 = e1x * e1x + e1y * e1y + e1z * e1z;

    float denom = fmaxf(area2, 1e-12f);
    double rs   = 1.0 / sqrt((double)denom);
    float nnx = (float)(nx * rs), nny = (float)(ny * rs), nnz = (float)(nz * rs);

    float inv00 = 1.0f / fmaxf(dot00, 1e-12f);
    float inv11 = 1.0f / fmaxf(dot11, 1e-12f);
    float abab  = dot00 - 2.0f * dot01 + dot11;
    float invab = 1.0f / fmaxf(abab, 1e-12f);
    float dt    = (area2 >= 4e-10f) ? denom : -1.0f;
    float c12   = dot00 - dot01;

    float4* q = pre + (size_t)i * 6;
    q[0] = make_float4(v0x, v0y, v0z, dt);
    q[1] = make_float4(e0x, e0y, e0z, dot00);
    q[2] = make_float4(e1x, e1y, e1z, dot11);
    q[3] = make_float4(nnx, nny, nnz, dot01);
    q[4] = make_float4(inv00, inv11, c12, invab);
    q[5] = make_float4(abab, 0.0f, 0.0f, 0.0f);
}

// Two triangles packed as float2 halves -> v_pk_*_f32 halves instruction count.
struct TP {
    v2f v0x, v0y, v0z, dt;
    v2f e0x, e0y, e0z, d00;
    v2f e1x, e1y, e1z, d11;
    v2f nnx, nny, nnz, d01;
    v2f i00, i11, c12, iab;
    v2f ab;
};

__device__ __forceinline__ void load_pair(const float4* __restrict__ p6,
                                          int ta, int tb, TP& t) {
    const float4* qa = p6 + (size_t)ta * 6;
    const float4* qb = p6 + (size_t)tb * 6;
    float4 a0 = qa[0], a1 = qa[1], a2 = qa[2], a3 = qa[3], a4 = qa[4], a5 = qa[5];
    float4 b0 = qb[0], b1 = qb[1], b2 = qb[2], b3 = qb[3], b4 = qb[4], b5 = qb[5];
    t.v0x = (v2f){a0.x, b0.x}; t.v0y = (v2f){a0.y, b0.y}; t.v0z = (v2f){a0.z, b0.z}; t.dt  = (v2f){a0.w, b0.w};
    t.e0x = (v2f){a1.x, b1.x}; t.e0y = (v2f){a1.y, b1.y}; t.e0z = (v2f){a1.z, b1.z}; t.d00 = (v2f){a1.w, b1.w};
    t.e1x = (v2f){a2.x, b2.x}; t.e1y = (v2f){a2.y, b2.y}; t.e1z = (v2f){a2.z, b2.z}; t.d11 = (v2f){a2.w, b2.w};
    t.nnx = (v2f){a3.x, b3.x}; t.nny = (v2f){a3.y, b3.y}; t.nnz = (v2f){a3.z, b3.z}; t.d01 = (v2f){a3.w, b3.w};
    t.i00 = (v2f){a4.x, b4.x}; t.i11 = (v2f){a4.y, b4.y}; t.c12 = (v2f){a4.z, b4.z}; t.iab = (v2f){a4.w, b4.w};
    t.ab  = (v2f){a5.x, b5.x};
}

// point (block-uniform scalars, live in SGPRs) vs 2 packed triangles
__device__ __forceinline__ void pair_body(float px, float py, float pz,
                                          const TP& g, v2f& dmin) {
    v2f dx = px - g.v0x, dy = py - g.v0y, dz = pz - g.v0z;
    v2f dd = dx * dx + dy * dy + dz * dz;
    v2f a0 = g.e0x * dx + g.e0y * dy + g.e0z * dz;
    v2f a1 = g.e1x * dx + g.e1y * dy + g.e1z * dz;
    v2f dn = g.nnx * dx + g.nny * dy + g.nnz * dz;

    v2f U = g.d11 * a0 - g.d01 * a1;
    v2f V = g.d00 * a1 - g.d01 * a0;
    v2f W = g.dt - (U + V);
    v2f plane = dn * dn;

    v2f a02 = a0 + a0;
    v2f m1 = a0 * g.i00;
    v2f t1; t1.x = fminf(fmaxf(m1.x, 0.f), 1.f); t1.y = fminf(fmaxf(m1.y, 0.f), 1.f);
    v2f s1 = dd + t1 * (t1 * g.d00 - a02);
    v2f a12 = a1 + a1;
    v2f m2 = a1 * g.i11;
    v2f t2; t2.x = fminf(fmaxf(m2.x, 0.f), 1.f); t2.y = fminf(fmaxf(m2.y, 0.f), 1.f);
    v2f s2 = dd + t2 * (t2 * g.d11 - a12);
    v2f pab  = (g.c12 + a1) - a0;
    v2f papa = (dd - a02) + g.d00;
    v2f m3 = pab * g.iab;
    v2f t3; t3.x = fminf(fmaxf(m3.x, 0.f), 1.f); t3.y = fminf(fmaxf(m3.y, 0.f), 1.f);
    v2f s3 = papa + t3 * (t3 * g.ab - (pab + pab));

    float ex = fminf(fminf(s1.x, s2.x), s3.x);           // v_min3
    float ey = fminf(fminf(s1.y, s2.y), s3.y);
    float ix = fminf(fminf(U.x, V.x), W.x);              // v_min3
    float iy = fminf(fminf(U.y, V.y), W.y);
    float rx = (ix >= 0.f) ? plane.x : ex;
    float ry = (iy >= 0.f) ? plane.y : ey;
    dmin.x = fminf(dmin.x, rx);
    dmin.y = fminf(dmin.y, ry);
}

// Grid: 2048 blocks x 256 threads (4 waves), 4 blocks/CU (VGPR<=128 via launch_bounds).
// block -> (batch = blk>>9, point-group = blk&511 -> 16 points).
// lane = triangle slot: wave w holds tris w*256 + {lane,+64,+128,+192} in REGISTERS.
// 16-point inner loop: pure VALU (points via s_load broadcast, per-lane M[16] acc,
// zero DS/shuffle ops). One LDS transpose-reduce per block (~2% overhead).
__global__ __launch_bounds__(256, 4) void rast_main(const float* __restrict__ pts,
                                                    const float4* __restrict__ pre,
                                                    float* __restrict__ out) {
    int blk  = blockIdx.x;
    int b    = blk >> 9;          // batch
    int pg   = blk & 511;         // point group of 16
    int base = (b << 13) + (pg << 4);
    int t    = threadIdx.x;
    int lane = t & 63;
    int wave = __builtin_amdgcn_readfirstlane(t >> 6);   // 0..3

    const float4* p6 = pre + (size_t)b * 1024 * 6;
    int t0 = wave * 256 + lane;

    TP g0, g1;
    load_pair(p6, t0,       t0 + 64,  g0);
    load_pair(p6, t0 + 128, t0 + 192, g1);

    const float* sp = pts + (size_t)base * 3;   // 48 floats, block-uniform -> s_load

    float M[16];
#pragma unroll
    for (int j = 0; j < 16; ++j) {
        float px = sp[j * 3 + 0], py = sp[j * 3 + 1], pz = sp[j * 3 + 2];
        v2f d = (v2f){3.4e38f, 3.4e38f};
        pair_body(px, py, pz, g0, d);
        pair_body(px, py, pz, g1, d);
        M[j] = fminf(d.x, d.y);
    }

    // --- block reduce: min over 256 threads for each of 16 points ---
    __shared__ float red[256 * 16];      // [thread][point], 16 KB
#pragma unroll
    for (int j = 0; j < 16; ++j) red[t * 16 + j] = M[j];
    __syncthreads();

    int p = t & 15, g = t >> 4;          // 16 groups x 16 source-threads
    float m = 3.4e38f;
#pragma unroll
    for (int s = 0; s < 16; ++s) m = fminf(m, red[(g * 16 + s) * 16 + p]);
    __shared__ float part[256];          // [group][point]
    part[t] = m;
    __syncthreads();
    if (t < 16) {
        float mm = part[t];
#pragma unroll
        for (int g2 = 1; g2 < 16; ++g2) mm = fminf(mm, part[g2 * 16 + t]);
        out[base + t] = __expf(-ALPHA * mm);
    }
}

extern "C" void kernel_launch(void* const* d_in, const int* in_sizes, int n_in,
                              void* d_out, int out_size, void* d_ws, size_t ws_size,
                              hipStream_t stream) {
    const float* pts = (const float*)d_in[0];   // (4, 8192, 3)
    const float* tv  = (const float*)d_in[1];   // (4, 1024, 3, 3)
    float* out = (float*)d_out;                 // (4, 8192)
    float4* pre = (float4*)d_ws;                // 4096 * 6 float4 = 384 KB

    rast_pre<<<16, 256, 0, stream>>>(tv, pre);
    rast_main<<<2048, 256, 0, stream>>>(pts, pre, out);
}

// Round 9
// 86.138 us; speedup vs baseline: 1.3681x; 1.0143x over previous
//
#include <hip/hip_runtime.h>
#include <hip/hip_bf16.h>

#define ALPHA 100.0f

typedef float v2f __attribute__((ext_vector_type(2)));

// Per-triangle precomputed invariants: 6 x float4 = 96 B
//  q0: v0.xyz, dt   q1: e0.xyz, dot00   q2: e1.xyz, dot11
//  q3: nn.xyz, dot01 (nn = n * rsqrt(denom))
//  q4: inv00, inv11, c12, invab   q5: abab, -, -, -
__global__ __launch_bounds__(256) void rast_pre(const float* __restrict__ tv,
                                                float4* __restrict__ pre) {
    int i = blockIdx.x * 256 + threadIdx.x;   // 0..4095
    if (i >= 4096) return;
    const float* t = tv + (size_t)i * 9;
    float v0x = t[0], v0y = t[1], v0z = t[2];
    float v1x = t[3], v1y = t[4], v1z = t[5];
    float v2x = t[6], v2y = t[7], v2z = t[8];

    float e0x = v1x - v0x, e0y = v1y - v0y, e0z = v1z - v0z;
    float e1x = v2x - v0x, e1y = v2y - v0y, e1z = v2z - v0z;

    float nx = e0y * e1z - e0z * e1y;
    float ny = e0z * e1x - e0x * e1z;
    float nz = e0x * e1y - e0y * e1x;
    float area2 = nx * nx + ny * ny + nz * nz;

    float dot00 = e0x * e0x + e0y * e0y + e0z * e0z;
    float dot01 = e0x * e1x + e0y * e1y + e0z * e1z;
    float dot11 = e1x * e1x + e1y * e1y + e1z * e1z;

    float denom = fmaxf(area2, 1e-12f);
    double rs   = 1.0 / sqrt((double)denom);
    float nnx = (float)(nx * rs), nny = (float)(ny * rs), nnz = (float)(nz * rs);

    float inv00 = 1.0f / fmaxf(dot00, 1e-12f);
    float inv11 = 1.0f / fmaxf(dot11, 1e-12f);
    float abab  = dot00 - 2.0f * dot01 + dot11;
    float invab = 1.0f / fmaxf(abab, 1e-12f);
    float dt    = (area2 >= 4e-10f) ? denom : -1.0f;
    float c12   = dot00 - dot01;

    float4* q = pre + (size_t)i * 6;
    q[0] = make_float4(v0x, v0y, v0z, dt);
    q[1] = make_float4(e0x, e0y, e0z, dot00);
    q[2] = make_float4(e1x, e1y, e1z, dot11);
    q[3] = make_float4(nnx, nny, nnz, dot01);
    q[4] = make_float4(inv00, inv11, c12, invab);
    q[5] = make_float4(abab, 0.0f, 0.0f, 0.0f);
}

// Two triangles packed as float2 halves (packing halves instruction count;
// fp32 VALU throughput is FLOP-bound either way).
struct TP {
    v2f v0x, v0y, v0z, dt;
    v2f e0x, e0y, e0z, d00;
    v2f e1x, e1y, e1z, d11;
    v2f nnx, nny, nnz, d01;
    v2f i00, i11, c12, iab;
    v2f ab;
};

__device__ __forceinline__ void load_pair(const float4* __restrict__ p6,
                                          int ta, int tb, TP& t) {
    const float4* qa = p6 + (size_t)ta * 6;
    const float4* qb = p6 + (size_t)tb * 6;
    float4 a0 = qa[0], a1 = qa[1], a2 = qa[2], a3 = qa[3], a4 = qa[4], a5 = qa[5];
    float4 b0 = qb[0], b1 = qb[1], b2 = qb[2], b3 = qb[3], b4 = qb[4], b5 = qb[5];
    t.v0x = (v2f){a0.x, b0.x}; t.v0y = (v2f){a0.y, b0.y}; t.v0z = (v2f){a0.z, b0.z}; t.dt  = (v2f){a0.w, b0.w};
    t.e0x = (v2f){a1.x, b1.x}; t.e0y = (v2f){a1.y, b1.y}; t.e0z = (v2f){a1.z, b1.z}; t.d00 = (v2f){a1.w, b1.w};
    t.e1x = (v2f){a2.x, b2.x}; t.e1y = (v2f){a2.y, b2.y}; t.e1z = (v2f){a2.z, b2.z}; t.d11 = (v2f){a2.w, b2.w};
    t.nnx = (v2f){a3.x, b3.x}; t.nny = (v2f){a3.y, b3.y}; t.nnz = (v2f){a3.z, b3.z}; t.d01 = (v2f){a3.w, b3.w};
    t.i00 = (v2f){a4.x, b4.x}; t.i11 = (v2f){a4.y, b4.y}; t.c12 = (v2f){a4.z, b4.z}; t.iab = (v2f){a4.w, b4.w};
    t.ab  = (v2f){a5.x, b5.x};
}

// point (block-uniform scalars -> SGPRs) vs 2 packed triangles; returns min dist_sq
__device__ __forceinline__ float pair_min(float px, float py, float pz, const TP& g) {
    v2f dx = px - g.v0x, dy = py - g.v0y, dz = pz - g.v0z;
    v2f dd = dx * dx + dy * dy + dz * dz;
    v2f a0 = g.e0x * dx + g.e0y * dy + g.e0z * dz;
    v2f a1 = g.e1x * dx + g.e1y * dy + g.e1z * dz;
    v2f dn = g.nnx * dx + g.nny * dy + g.nnz * dz;

    v2f U = g.d11 * a0 - g.d01 * a1;
    v2f V = g.d00 * a1 - g.d01 * a0;
    v2f W = g.dt - (U + V);
    v2f plane = dn * dn;

    v2f a02 = a0 + a0;
    v2f m1 = a0 * g.i00;
    v2f t1; t1.x = fminf(fmaxf(m1.x, 0.f), 1.f); t1.y = fminf(fmaxf(m1.y, 0.f), 1.f);
    v2f s1 = dd + t1 * (t1 * g.d00 - a02);
    v2f a12 = a1 + a1;
    v2f m2 = a1 * g.i11;
    v2f t2; t2.x = fminf(fmaxf(m2.x, 0.f), 1.f); t2.y = fminf(fmaxf(m2.y, 0.f), 1.f);
    v2f s2 = dd + t2 * (t2 * g.d11 - a12);
    v2f pab  = (g.c12 + a1) - a0;
    v2f papa = (dd - a02) + g.d00;
    v2f m3 = pab * g.iab;
    v2f t3; t3.x = fminf(fmaxf(m3.x, 0.f), 1.f); t3.y = fminf(fmaxf(m3.y, 0.f), 1.f);
    v2f s3 = papa + t3 * (t3 * g.ab - (pab + pab));

    float ex = fminf(fminf(s1.x, s2.x), s3.x);           // v_min3
    float ey = fminf(fminf(s1.y, s2.y), s3.y);
    float ix = fminf(fminf(U.x, V.x), W.x);              // v_min3
    float iy = fminf(fminf(U.y, V.y), W.y);
    float rx = (ix >= 0.f) ? plane.x : ex;
    float ry = (iy >= 0.f) ? plane.y : ey;
    return fminf(rx, ry);
}

// Grid: 1024 blocks x 512 threads (8 waves), launch_bounds(512,4) -> VGPR<=128.
// block -> (batch = blk>>8, point-group = blk&255 -> 32 points).
// Wave w (0..7) holds tris w*128 + {lane, lane+64} in REGISTERS (one TP, ~42 VGPR).
// 32-point inner loop: pure VALU, per-lane M[32], zero DS ops.
// Block reduce: two chunks of 16 points through a padded [512][17] LDS tile
// (stride 17 words -> conflict-free writes and reads).
__global__ __launch_bounds__(512, 4) void rast_main(const float* __restrict__ pts,
                                                    const float4* __restrict__ pre,
                                                    float* __restrict__ out) {
    int blk  = blockIdx.x;
    int b    = blk >> 8;          // batch
    int pg   = blk & 255;         // point group of 32
    int base = (b << 13) + (pg << 5);
    int t    = threadIdx.x;
    int lane = t & 63;
    int wave = __builtin_amdgcn_readfirstlane(t >> 6);   // 0..7

    const float4* p6 = pre + (size_t)b * 1024 * 6;
    int ta = wave * 128 + lane;

    TP g0;
    load_pair(p6, ta, ta + 64, g0);

    const float* sp = pts + (size_t)base * 3;   // 96 floats, block-uniform -> s_load

    float M[32];
#pragma unroll
    for (int j = 0; j < 32; ++j) {
        M[j] = pair_min(sp[j * 3 + 0], sp[j * 3 + 1], sp[j * 3 + 2], g0);
    }

    // --- block reduce: min over 512 threads for each of 32 points, 2 chunks ---
    __shared__ float red[512 * 17];      // padded: stride 17 words, 34.8 KB
    __shared__ float part[512];
#pragma unroll
    for (int c = 0; c < 2; ++c) {
        if (c) __syncthreads();
#pragma unroll
        for (int j2 = 0; j2 < 16; ++j2) red[t * 17 + j2] = M[c * 16 + j2];
        __syncthreads();
        int p = t & 15, g = t >> 4;      // 32 groups x 16 source-threads
        float m = 3.4e38f;
#pragma unroll
        for (int s = 0; s < 16; ++s) m = fminf(m, red[(g * 16 + s) * 17 + p]);
        part[t] = m;
        __syncthreads();
        if (t < 16) {
            float mm = part[t];
#pragma unroll
            for (int g2 = 1; g2 < 32; ++g2) mm = fminf(mm, part[g2 * 16 + t]);
            out[base + c * 16 + t] = __expf(-ALPHA * mm);
        }
    }
}

extern "C" void kernel_launch(void* const* d_in, const int* in_sizes, int n_in,
                              void* d_out, int out_size, void* d_ws, size_t ws_size,
                              hipStream_t stream) {
    const float* pts = (const float*)d_in[0];   // (4, 8192, 3)
    const float* tv  = (const float*)d_in[1];   // (4, 1024, 3, 3)
    float* out = (float*)d_out;                 // (4, 8192)
    float4* pre = (float4*)d_ws;                // 4096 * 6 float4 = 384 KB

    rast_pre<<<16, 256, 0, stream>>>(tv, pre);
    rast_main<<<1024, 512, 0, stream>>>(pts, pre, out);
}